// Round 16
// baseline (2108.188 us; speedup 1.0000x reference)
//
#include <hip/hip_runtime.h>
#include <stdint.h>
#include <stddef.h>

// SwinV2-B stage-3 window attention, MI355X bf16-MFMA pipeline.
// Round 16: qkv switched to double-buffer 48KB LDS -> 3 blocks/CU
// (vmcnt(0) per K-tile, hidden by cross-block TLP); epilogue in two
// 32-row half-passes. Everything else identical to round 15 (best, 633.8us).
// Big ws layout (ws_size >= 543,178,752 B):
//   [0)            QKV bf16 [131072][1536]  (flat; attn overwrites q-cols)
//   [402653184)    XB  bf16 [131072][512]
//   [536870912)    CMB f32 [16w][16h][64][64]
//   [541065216)    SIG f32 [225][16] (pad 16K)
//   [541081600)    WQB bf16 [1536][512]
//   [542654464)    WPB bf16 [512][512]

typedef __attribute__((ext_vector_type(8))) short bf16x8;
typedef __attribute__((ext_vector_type(4))) float f32x4;
typedef __attribute__((ext_vector_type(4))) unsigned short us4;
typedef __attribute__((ext_vector_type(8))) unsigned short us8;
typedef unsigned short u16;
typedef unsigned int u32;

#define FENCE() asm volatile("" ::: "memory")
#define WAITV4() asm volatile("s_waitcnt vmcnt(4)" ::: "memory")
#define WAITV3() asm volatile("s_waitcnt vmcnt(3)" ::: "memory")
#define WAITV0() asm volatile("s_waitcnt vmcnt(0)" ::: "memory")
#define WAITL0() asm volatile("s_waitcnt lgkmcnt(0)" ::: "memory")

__device__ __forceinline__ u16 f2bf(float f) {
  union { __bf16 b; u16 u; } cv;
  cv.b = (__bf16)f;            // hardware RNE convert on gfx950
  return cv.u;
}
__device__ __forceinline__ float bf2f(u16 s) {
  return __uint_as_float(((u32)s) << 16);
}
__device__ __forceinline__ void gl_lds16(const void* g, void* l) {
  __builtin_amdgcn_global_load_lds(
      (const __attribute__((address_space(1))) u32*)g,
      (__attribute__((address_space(3))) u32*)l, 16, 0, 0);
}
__device__ __forceinline__ f32x4 mfma16(bf16x8 a, bf16x8 b, f32x4 c) {
  return __builtin_amdgcn_mfma_f32_16x16x32_bf16(a, b, c, 0, 0, 0);
}
__device__ __forceinline__ bf16x8 ldswz(const u16* p, int ks) {
  return *(const bf16x8*)((const u16*)((uintptr_t)p ^ (uintptr_t)(ks << 6)));
}

// ---------------- K1: merged prep (xconv | conv_w | sig16) ----------------

__global__ void prep_kernel(const float* __restrict__ X, u16* __restrict__ XB,
                            const float* __restrict__ QW, const float* __restrict__ PW,
                            u16* __restrict__ WQB, u16* __restrict__ WPB,
                            const float* __restrict__ CT, const float* __restrict__ W1,
                            const float* __restrict__ B1, const float* __restrict__ W2,
                            float* __restrict__ SIG) {
  const int b = blockIdx.x, tid = threadIdx.x;
  if (b < 32768) {                               // --- xconv ---
    size_t idx = (size_t)b * 256 + tid;          // 8,388,608 threads, 8 f32 each
    float4 a = ((const float4*)X)[idx * 2];
    float4 c = ((const float4*)X)[idx * 2 + 1];
    us8 o;
    o[0] = f2bf(a.x); o[1] = f2bf(a.y); o[2] = f2bf(a.z); o[3] = f2bf(a.w);
    o[4] = f2bf(c.x); o[5] = f2bf(c.y); o[6] = f2bf(c.z); o[7] = f2bf(c.w);
    *(us8*)&XB[idx * 8] = o;
  } else if (b < 33792) {                        // --- conv_w ---
    int idx = (b - 32768) * 256 + tid;           // 262144 float4 chunks
    const int NQ = 1536 * 512 / 4;               // 196608
    float4 v; u16* dst;
    if (idx < NQ) { v = ((const float4*)QW)[idx]; dst = WQB + (size_t)idx * 4; }
    else { int k = idx - NQ; v = ((const float4*)PW)[k]; dst = WPB + (size_t)k * 4; }
    us4 u; u.x = f2bf(v.x); u.y = f2bf(v.y); u.z = f2bf(v.z); u.w = f2bf(v.w);
    *(us4*)dst = u;
  } else {                                       // --- sig16 ---
    int i = b - 33792;                           // 0..224
    float c0 = CT[i * 2 + 0], c1 = CT[i * 2 + 1];
    float a[16];
    #pragma unroll
    for (int hh = 0; hh < 16; ++hh) a[hh] = 0.f;
    #pragma unroll
    for (int jj = 0; jj < 2; ++jj) {
      int j = tid + jj * 256;
      float h = fmaxf(c0 * W1[j * 2 + 0] + c1 * W1[j * 2 + 1] + B1[j], 0.f);
      #pragma unroll
      for (int hh = 0; hh < 16; ++hh) a[hh] += h * W2[hh * 512 + j];
    }
    __shared__ float red[4][16];
    #pragma unroll
    for (int hh = 0; hh < 16; ++hh) {
      float v = a[hh];
      for (int m = 1; m < 64; m <<= 1) v += __shfl_xor(v, m);
      if ((tid & 63) == 0) red[tid >> 6][hh] = v;
    }
    __syncthreads();
    if (tid < 16) {
      float v = red[0][tid] + red[1][tid] + red[2][tid] + red[3][tid];
      SIG[i * 16 + tid] = 16.f / (1.f + __expf(-v));
    }
  }
}

// ---------------- K2: qkv GEMM (double-buffer, 3 blocks/CU) + cmb tail ----------------
// 128x256, BK=32, 8 waves, 2 bufs x (A 8KB + B 16KB) = 48KB LDS.
// P0(t): read A+B01 frags of buf[t&1]; stage(t+1) into buf[(t+1)&1] (WAR-safe:
// its last reads sealed by P1(t-1)'s trailing barrier); bar; lgkm0; 8 MFMA; bar.
// P1(t): read B23; vmcnt(0) (t+1 resident; ~1.5 phases of slack, hidden by
// 3-block TLP); bar; lgkm0; 8 MFMA; bar.

__global__ __launch_bounds__(512, 6) void qkv_g32(
    const u16* __restrict__ XB, const u16* __restrict__ WB,
    const float* __restrict__ QB, const float* __restrict__ VB,
    u16* __restrict__ QKV,
    const float* __restrict__ SIG, const float* __restrict__ MASK,
    const int* __restrict__ RPI, float* __restrict__ CMB) {
  __shared__ u16 S[24576];  // 2 x (A 4096 + B 8192) u16 = 49152 B
  const int tid = threadIdx.x, lane = tid & 63, w = tid >> 6;
  int bid = blockIdx.x;
  if (bid >= 6144) {                             // --- cmb tail (256 blocks) ---
    int b2 = bid - 6144;
    int mw = b2 >> 4, h = b2 & 15;
    const float* mrow = &MASK[(size_t)mw * 4096];
    float* crow = &CMB[(size_t)b2 * 4096];
    #pragma unroll
    for (int it = 0; it < 8; ++it) {
      int nm = it * 512 + tid;
      crow[nm] = SIG[RPI[nm] * 16 + h] + mrow[nm];
    }
    return;
  }
  int swz = (bid & 7) * 768 + (bid >> 3);         // bijective XCD swizzle
  const int mt = swz / 6, nt = swz - mt * 6;
  const long m0 = (long)mt * 128, n0 = (long)nt * 256;
  const int wm = w >> 2, wn = w & 3;              // 2M x 4N waves; wave tile 64x64
  const int fr = lane & 15, lg = lane >> 4;
  const int fsw = (lg ^ ((fr >> 1) & 3)) << 3;    // swizzled chunk (u16 units)
  const f32x4 zf = {0.f, 0.f, 0.f, 0.f};

  f32x4 acc[4][4];
  #pragma unroll
  for (int mi = 0; mi < 4; ++mi)
    #pragma unroll
    for (int ni = 0; ni < 4; ++ni) acc[mi][ni] = zf;

  const int arow = tid >> 2;
  const int asc = (tid & 3) ^ ((arow >> 1) & 3);
  const u16* aSrc = &XB[(size_t)(m0 + arow) * 512 + asc * 8];
  const u16* bSrc0 = &WB[(size_t)(n0 + arow) * 512 + asc * 8];          // rows 0-127
  const u16* bSrc1 = &WB[(size_t)(n0 + 128 + arow) * 512 + asc * 8];    // rows 128-255

  auto stageT = [&](int kt) {                     // A + both B halves (3 loads)
    int dst = (kt & 1) * 12288;
    gl_lds16(aSrc + kt * 32, &S[dst + w * 512]);
    gl_lds16(bSrc0 + kt * 32, &S[dst + 4096 + w * 512]);
    gl_lds16(bSrc1 + kt * 32, &S[dst + 8192 + w * 512]);
  };

  bf16x8 af[4], bf[2];

  stageT(0);
  WAITV0();
  FENCE(); __builtin_amdgcn_s_barrier(); FENCE();

  #pragma unroll
  for (int t = 0; t < 16; ++t) {
    const int Sb = (t & 1) * 12288;
    // ---- P0 ----
    #pragma unroll
    for (int m = 0; m < 4; ++m)
      af[m] = *(const bf16x8*)&S[Sb + (wm * 64 + m * 16 + fr) * 32 + fsw];
    #pragma unroll
    for (int n = 0; n < 2; ++n)
      bf[n] = *(const bf16x8*)&S[Sb + 4096 + (wn * 64 + n * 16 + fr) * 32 + fsw];
    if (t + 1 <= 15) stageT(t + 1);
    FENCE(); __builtin_amdgcn_s_barrier(); FENCE();
    WAITL0(); __builtin_amdgcn_sched_barrier(0);
    __builtin_amdgcn_s_setprio(1);
    #pragma unroll
    for (int m = 0; m < 4; ++m)
      #pragma unroll
      for (int n = 0; n < 2; ++n)
        acc[m][n] = mfma16(af[m], bf[n], acc[m][n]);
    __builtin_amdgcn_s_setprio(0);
    FENCE(); __builtin_amdgcn_s_barrier(); FENCE();
    // ---- P1 ----
    #pragma unroll
    for (int n = 0; n < 2; ++n)
      bf[n] = *(const bf16x8*)&S[Sb + 4096 + (wn * 64 + (n + 2) * 16 + fr) * 32 + fsw];
    if (t + 1 <= 15) { WAITV0(); }
    FENCE(); __builtin_amdgcn_s_barrier(); FENCE();
    WAITL0(); __builtin_amdgcn_sched_barrier(0);
    __builtin_amdgcn_s_setprio(1);
    #pragma unroll
    for (int m = 0; m < 4; ++m)
      #pragma unroll
      for (int n = 0; n < 2; ++n)
        acc[m][n + 2] = mfma16(af[m], bf[n], acc[m][n + 2]);
    __builtin_amdgcn_s_setprio(0);
    FENCE(); __builtin_amdgcn_s_barrier(); FENCE();
  }

  // Epilogue in two 32-row half-passes (per-wave [32][72] = 4608B, 8 waves = 36864B).
  u16* eb = &S[w * 2304];
  #pragma unroll
  for (int half = 0; half < 2; ++half) {
    #pragma unroll
    for (int ni = 0; ni < 4; ++ni) {
      const long c = n0 + wn * 64 + ni * 16 + fr;
      float bias = (c < 512) ? QB[c] : (c < 1024 ? 0.f : VB[c - 1024]);
      #pragma unroll
      for (int mm = 0; mm < 2; ++mm) {
        const int mi = half * 2 + mm;
        #pragma unroll
        for (int r = 0; r < 4; ++r)
          eb[(mm * 16 + lg * 4 + r) * 72 + ni * 16 + fr] = f2bf(acc[mi][ni][r] + bias);
      }
    }
    WAITL0(); __builtin_amdgcn_sched_barrier(0);
    #pragma unroll
    for (int j = 0; j < 4; ++j) {
      int unit = j * 64 + lane;
      int row32 = unit >> 3, c16 = unit & 7;
      us8 v = *(const us8*)&eb[row32 * 72 + c16 * 8];
      *(us8*)&QKV[(size_t)(m0 + wm * 64 + half * 32 + row32) * 1536 +
                  n0 + wn * 64 + c16 * 8] = v;
    }
    WAITL0(); __builtin_amdgcn_sched_barrier(0);   // reads done before next half's writes
  }
}

// ============ 128x256 / BK=32 / 8-wave / triple-buffer pipeline (r9, for proj) ============

#define GEMM32_KLOOP()                                                     \
  _Pragma("unroll")                                                        \
  for (int t = 0; t < 16; ++t) {                                           \
    const int Sb = (t % 3) * 12288;                                        \
    _Pragma("unroll")                                                      \
    for (int m = 0; m < 4; ++m)                                            \
      af[m] = *(const bf16x8*)&S[Sb + (wm * 64 + m * 16 + fr) * 32 + fsw]; \
    _Pragma("unroll")                                                      \
    for (int n = 0; n < 2; ++n)                                            \
      bf[n] = *(const bf16x8*)&S[Sb + 4096 + (wn * 64 + n * 16 + fr) * 32 + fsw]; \
    if (t + 2 <= 15) stageB(t + 2);                                        \
    FENCE(); __builtin_amdgcn_s_barrier(); FENCE();                        \
    WAITL0(); __builtin_amdgcn_sched_barrier(0);                           \
    __builtin_amdgcn_s_setprio(1);                                         \
    _Pragma("unroll")                                                      \
    for (int m = 0; m < 4; ++m)                                            \
      _Pragma("unroll")                                                    \
      for (int n = 0; n < 2; ++n)                                          \
        acc[m][n] = mfma16(af[m], bf[n], acc[m][n]);                       \
    __builtin_amdgcn_s_setprio(0);                                         \
    FENCE(); __builtin_amdgcn_s_barrier(); FENCE();                        \
    _Pragma("unroll")                                                      \
    for (int n = 0; n < 2; ++n)                                            \
      bf[n] = *(const bf16x8*)&S[Sb + 4096 + (wn * 64 + (n + 2) * 16 + fr) * 32 + fsw]; \
    if (t + 3 <= 15) stageA(t + 3);                                        \
    if (t <= 12) { WAITV4(); }                                             \
    else if (t == 13) { WAITV3(); }                                        \
    else if (t == 14) { WAITV0(); }                                        \
    FENCE(); __builtin_amdgcn_s_barrier(); FENCE();                        \
    WAITL0(); __builtin_amdgcn_sched_barrier(0);                           \
    __builtin_amdgcn_s_setprio(1);                                         \
    _Pragma("unroll")                                                      \
    for (int m = 0; m < 4; ++m)                                            \
      _Pragma("unroll")                                                    \
      for (int n = 0; n < 2; ++n)                                          \
        acc[m][n + 2] = mfma16(af[m], bf[n], acc[m][n + 2]);               \
    __builtin_amdgcn_s_setprio(0);                                         \
    FENCE(); __builtin_amdgcn_s_barrier(); FENCE();                        \
  }

// ---------------- K4: proj GEMM (r9) ----------------

__global__ __launch_bounds__(512, 4) void proj_g32(
    const u16* __restrict__ A, const u16* __restrict__ WB,
    const float* __restrict__ PB, float* __restrict__ OUT) {
  __shared__ u16 S[36864];
  const int tid = threadIdx.x, lane = tid & 63, w = tid >> 6;
  int bid = blockIdx.x;                           // 2048 = 1024m x 2n
  int swz = (bid & 7) * 256 + (bid >> 3);
  const int mt = swz >> 1, nt = swz & 1;
  const long m0 = (long)mt * 128, n0 = (long)nt * 256;
  const int wm = w >> 2, wn = w & 3;
  const int fr = lane & 15, lg = lane >> 4;
  const int fsw = (lg ^ ((fr >> 1) & 3)) << 3;
  const f32x4 zf = {0.f, 0.f, 0.f, 0.f};

  f32x4 acc[4][4];
  #pragma unroll
  for (int mi = 0; mi < 4; ++mi)
    #pragma unroll
    for (int ni = 0; ni < 4; ++ni) acc[mi][ni] = zf;

  const int arow = tid >> 2;
  const int asc = (tid & 3) ^ ((arow >> 1) & 3);
  const u16* aSrc = &A[(size_t)(m0 + arow) * 1536 + asc * 8];           // lda 1536
  const u16* bSrc0 = &WB[(size_t)(n0 + arow) * 512 + asc * 8];
  const u16* bSrc1 = &WB[(size_t)(n0 + 128 + arow) * 512 + asc * 8];

  auto stageA = [&](int kt) {
    gl_lds16(aSrc + kt * 32, &S[(kt % 3) * 12288 + w * 512]);
  };
  auto stageB = [&](int kt) {
    gl_lds16(bSrc0 + kt * 32, &S[(kt % 3) * 12288 + 4096 + w * 512]);
    gl_lds16(bSrc1 + kt * 32, &S[(kt % 3) * 12288 + 8192 + w * 512]);
  };

  bf16x8 af[4], bf[2];

  stageA(0); stageB(0); stageA(1); stageB(1); stageA(2);
  WAITV4();
  FENCE(); __builtin_amdgcn_s_barrier(); FENCE();

  GEMM32_KLOOP()

  #pragma unroll
  for (int ni = 0; ni < 4; ++ni) {
    const long c = n0 + wn * 64 + ni * 16 + fr;
    float bias = PB[c];
    #pragma unroll
    for (int mi = 0; mi < 4; ++mi)
      #pragma unroll
      for (int r = 0; r < 4; ++r) {
        long row = m0 + wm * 64 + mi * 16 + lg * 4 + r;
        OUT[row * 512 + c] = acc[mi][ni][r] + bias;
      }
  }
}

// ---------------- qkv fallback (small ws): reg-staged A, 128x128 ----------------

__global__ __launch_bounds__(256, 2) void qkv_gemm_rs(
    const float* __restrict__ X, const u16* __restrict__ WB,
    const float* __restrict__ QB, const float* __restrict__ VB,
    u16* __restrict__ QKV) {
  __shared__ u16 As[128 * 64];
  __shared__ u16 Bs[128 * 64];
  const int tid = threadIdx.x, lane = tid & 63, w = tid >> 6;
  int bid = blockIdx.x;
  int swz = (bid & 7) * 1536 + (bid >> 3);
  const int mt = swz / 12, nt = swz - mt * 12;
  const long m0 = (long)mt * 128, n0 = (long)nt * 128;
  const int wm = w >> 1, wn = w & 1;
  const f32x4 zf = {0.f, 0.f, 0.f, 0.f};

  f32x4 acc[4][4];
  #pragma unroll
  for (int mi = 0; mi < 4; ++mi)
    #pragma unroll
    for (int ni = 0; ni < 4; ++ni) acc[mi][ni] = zf;

  const int fr = lane & 15;
  const int fsw = ((lane >> 4) ^ (lane & 7)) * 8;
  const u16* Ap = &As[(wm * 64 + fr) * 64 + fsw];
  const u16* Bp = &Bs[(wn * 64 + fr) * 64 + fsw];

  for (int t = 0; t < 8; ++t) {
    float4 av[8];
    #pragma unroll
    for (int i = 0; i < 8; ++i) {
      int ch = tid + (i << 8);
      int row = ch >> 4, kc = ch & 15;
      av[i] = *(const float4*)&X[(m0 + row) * 512 + t * 64 + kc * 4];
    }
    #pragma unroll
    for (int i = 0; i < 4; ++i) {
      int ch = ((w << 2) + i) * 64 + lane;
      int row = ch >> 3, kc = (ch & 7) ^ (row & 7);
      gl_lds16(&WB[(n0 + row) * 512 + t * 64 + kc * 8], &Bs[((w << 2) + i) * 512]);
    }
    #pragma unroll
    for (int i = 0; i < 8; ++i) {
      int ch = tid + (i << 8);
      int row = ch >> 4, kc = ch & 15;
      int kcs = kc ^ ((row & 7) << 1);
      us4 u; u.x = f2bf(av[i].x); u.y = f2bf(av[i].y); u.z = f2bf(av[i].z); u.w = f2bf(av[i].w);
      *(us4*)&As[row * 64 + kcs * 4] = u;
    }
    __syncthreads();
    #pragma unroll
    for (int ks = 0; ks < 2; ++ks) {
      bf16x8 af[4], bfr[4];
      #pragma unroll
      for (int mi = 0; mi < 4; ++mi) af[mi] = ldswz(Ap + mi * 1024, ks);
      #pragma unroll
      for (int ni = 0; ni < 4; ++ni) bfr[ni] = ldswz(Bp + ni * 1024, ks);
      #pragma unroll
      for (int mi = 0; mi < 4; ++mi)
        #pragma unroll
        for (int ni = 0; ni < 4; ++ni)
          acc[mi][ni] = mfma16(af[mi], bfr[ni], acc[mi][ni]);
    }
    __syncthreads();
  }

  #pragma unroll
  for (int ni = 0; ni < 4; ++ni) {
    const long c = n0 + wn * 64 + ni * 16 + (lane & 15);
    float bias = (c < 512) ? QB[c] : (c < 1024 ? 0.f : VB[c - 1024]);
    #pragma unroll
    for (int mi = 0; mi < 4; ++mi)
      #pragma unroll
      for (int r = 0; r < 4; ++r) {
        long row = m0 + wm * 64 + mi * 16 + (lane >> 4) * 4 + r;
        QKV[row * 1536 + c] = f2bf(acc[mi][ni][r] + bias);
      }
  }
}

__global__ void cmb_kernel(const float* __restrict__ SIG, const float* __restrict__ MASK,
                           const int* __restrict__ RPI, float* __restrict__ CMB) {
  int b = blockIdx.x;
  int w = b >> 4, h = b & 15;
  int tid = threadIdx.x;
  const float* mrow = &MASK[(size_t)w * 4096];
  float* crow = &CMB[(size_t)b * 4096];
  #pragma unroll
  for (int it = 0; it < 16; ++it) {
    int nm = it * 256 + tid;
    crow[nm] = SIG[RPI[nm] * 16 + h] + mrow[nm];
  }
}

// ---------------- K3: attention (r10): one (window, head) per wave ----------------

__global__ __launch_bounds__(256, 3) void attn_wh(
    u16* __restrict__ QKV, const float* __restrict__ CMB, const float* __restrict__ LS) {
  __shared__ u16 smu[26112];     // 4 waves x (4352 + 2176) u16 = 52224 B
  const int tid = threadIdx.x, lane = tid & 63, w = tid >> 6;
  const int b = blockIdx.x;
  const int win = b >> 2;        // 0..2047
  const int h = (b & 3) * 4 + w; // head 0..15
  const int wi = win & 15;
  const size_t base = (size_t)win * 64 * 1536;
  const int fr = lane & 15, lg = lane >> 4;
  u16* ps = &smu[w * 6528];      // [64][68]
  u16* vt = ps + 4352;           // [32][68]  (V^T: [d][key])
  const float scale = __expf(fminf(LS[h], 4.6051702f));
  const float* cp = &CMB[((size_t)(wi * 16 + h)) << 12];
  const f32x4 zf = {0.f, 0.f, 0.f, 0.f};

  us8 vrow[4];
  #pragma unroll
  for (int c = 0; c < 4; ++c)
    vrow[c] = *(const us8*)&QKV[base + (size_t)lane * 1536 + 1024 + h * 32 + c * 8];

  f32x4 acc[4][4];
  #pragma unroll
  for (int m = 0; m < 4; ++m)
    #pragma unroll
    for (int n = 0; n < 4; ++n)
      #pragma unroll
      for (int r = 0; r < 4; ++r)
        acc[m][n][r] = cp[(m * 16 + lg * 4 + r) * 64 + n * 16 + fr];

  bf16x8 af[4], bk[4];
  #pragma unroll
  for (int m = 0; m < 4; ++m) {
    us8 qv = *(const us8*)&QKV[base + (size_t)(m * 16 + fr) * 1536 + h * 32 + lg * 8];
    float qf[8]; float ss = 0.f;
    #pragma unroll
    for (int j = 0; j < 8; ++j) { qf[j] = bf2f(qv[j]); ss += qf[j] * qf[j]; }
    ss += __shfl_xor(ss, 16); ss += __shfl_xor(ss, 32);
    float rn = scale / fmaxf(sqrtf(ss), 1e-12f);
    union { us8 u; bf16x8 b; } cv;
    #pragma unroll
    for (int j = 0; j < 8; ++j) cv.u[j] = f2bf(qf[j] * rn);
    af[m] = cv.b;
  }
  #pragma unroll
  for (int m = 0; m < 4; ++m) {
    us8 kv = *(const us8*)&QKV[base + (size_t)(m * 16 + fr) * 1536 + 512 + h * 32 + lg * 8];
    float kf[8]; float ss = 0.f;
    #pragma unroll
    for (int j = 0; j < 8; ++j) { kf[j] = bf2f(kv[j]); ss += kf[j] * kf[j]; }
    ss += __shfl_xor(ss, 16); ss += __shfl_xor(ss, 32);
    float rn = 1.f / fmaxf(sqrtf(ss), 1e-12f);
    union { us8 u; bf16x8 b; } cv;
    #pragma unroll
    for (int j = 0; j < 8; ++j) cv.u[j] = f2bf(kf[j] * rn);
    bk[m] = cv.b;
  }

  #pragma unroll
  for (int m = 0; m < 4; ++m)
    #pragma unroll
    for (int n = 0; n < 4; ++n)
      acc[m][n] = mfma16(af[m], bk[n], acc[m][n]);

  #pragma unroll
  for (int c = 0; c < 4; ++c)
    #pragma unroll
    for (int j = 0; j < 8; ++j)
      vt[(c * 8 + j) * 68 + lane] = vrow[c][j];

  #pragma unroll
  for (int m = 0; m < 4; ++m)
    #pragma unroll
    for (int r = 0; r < 4; ++r) {
      float pv[4];
      float mx = -3.0e38f;
      #pragma unroll
      for (int n = 0; n < 4; ++n) { pv[n] = acc[m][n][r]; mx = fmaxf(mx, pv[n]); }
      mx = fmaxf(mx, __shfl_xor(mx, 1));
      mx = fmaxf(mx, __shfl_xor(mx, 2));
      mx = fmaxf(mx, __shfl_xor(mx, 4));
      mx = fmaxf(mx, __shfl_xor(mx, 8));
      float sum = 0.f;
      #pragma unroll
      for (int n = 0; n < 4; ++n) { pv[n] = __expf(pv[n] - mx); sum += pv[n]; }
      sum += __shfl_xor(sum, 1); sum += __shfl_xor(sum, 2);
      sum += __shfl_xor(sum, 4); sum += __shfl_xor(sum, 8);
      float inv = 1.f / sum;
      #pragma unroll
      for (int n = 0; n < 4; ++n)
        ps[(m * 16 + lg * 4 + r) * 68 + n * 16 + fr] = f2bf(pv[n] * inv);
    }

  WAITL0(); __builtin_amdgcn_sched_barrier(0);

  f32x4 o[4][2];
  #pragma unroll
  for (int m = 0; m < 4; ++m) { o[m][0] = zf; o[m][1] = zf; }
  #pragma unroll
  for (int m = 0; m < 4; ++m)
    #pragma unroll
    for (int ks = 0; ks < 2; ++ks) {
      bf16x8 ap = *(const bf16x8*)&ps[(m * 16 + fr) * 68 + ks * 32 + lg * 8];
      #pragma unroll
      for (int n2 = 0; n2 < 2; ++n2) {
        bf16x8 bv = *(const bf16x8*)&vt[(n2 * 16 + fr) * 68 + ks * 32 + lg * 8];
        o[m][n2] = mfma16(ap, bv, o[m][n2]);
      }
    }

  #pragma unroll
  for (int m = 0; m < 4; ++m)
    #pragma unroll
    for (int n2 = 0; n2 < 2; ++n2)
      #pragma unroll
      for (int r = 0; r < 4; ++r)
        QKV[base + (size_t)(m * 16 + lg * 4 + r) * 1536 + h * 32 + n2 * 16 + fr] =
            f2bf(o[m][n2][r]);
}

// ---------------- launch ----------------

extern "C" void kernel_launch(void* const* d_in, const int* in_sizes, int n_in,
                              void* d_out, int out_size, void* d_ws, size_t ws_size,
                              hipStream_t stream) {
  const float* X    = (const float*)d_in[0];
  const float* MASK = (const float*)d_in[1];
  const float* QW   = (const float*)d_in[2];
  const float* QB   = (const float*)d_in[3];
  const float* VB   = (const float*)d_in[4];
  const float* LS   = (const float*)d_in[5];
  const float* CW1  = (const float*)d_in[6];
  const float* CB1  = (const float*)d_in[7];
  const float* CW2  = (const float*)d_in[8];
  const float* PW   = (const float*)d_in[9];
  const float* PB   = (const float*)d_in[10];
  const float* CT   = (const float*)d_in[11];
  const int*   RPI  = (const int*)d_in[12];
  float* OUT = (float*)d_out;

  char* ws = (char*)d_ws;
  const bool big = ws_size >= 543178752ull;
  u16* QKV = (u16*)ws;                                    // 402,653,184 B
  u16* XB  = (u16*)(ws + 402653184ull);                   // 134,217,728 B (big only)
  size_t off = big ? 536870912ull : 402653184ull;
  float* CMB = (float*)(ws + off);  off += 4194304ull;    // 4 MB
  float* SIG = (float*)(ws + off);  off += 16384ull;
  u16*   WQB = (u16*)(ws + off);    off += 1572864ull;
  u16*   WPB = (u16*)(ws + off);

  if (big) {
    prep_kernel<<<34017, 256, 0, stream>>>(X, XB, QW, PW, WQB, WPB,
                                           CT, CW1, CB1, CW2, SIG);
    qkv_g32<<<6400, 512, 0, stream>>>(XB, WQB, QB, VB, QKV, SIG, MASK, RPI, CMB);
  } else {
    prep_kernel<<<34017, 256, 0, stream>>>(X, XB, QW, PW, WQB, WPB,
                                           CT, CW1, CB1, CW2, SIG);
    cmb_kernel<<<256, 256, 0, stream>>>(SIG, MASK, RPI, CMB);
    qkv_gemm_rs<<<12288, 256, 0, stream>>>(X, WQB, QB, VB, QKV);
  }
  attn_wh<<<8192, 256, 0, stream>>>(QKV, CMB, LS);
  proj_g32<<<2048, 512, 0, stream>>>(QKV, WPB, PB, OUT);
}

// Round 17
// 662.963 us; speedup vs baseline: 3.1799x; 3.1799x over previous
//
#include <hip/hip_runtime.h>
#include <stdint.h>
#include <stddef.h>

// SwinV2-B stage-3 window attention, MI355X bf16-MFMA pipeline.
// Round 17: retest r16's double-buffer qkv (48KB LDS -> 3 blocks/CU) with the
// register cap fixed: __launch_bounds__(512,4) (r16's (512,6) capped VGPR at 40
// -> acc spilled to scratch -> 8.5GB traffic). Everything else = r15 (best).
// Big ws layout (ws_size >= 543,178,752 B):
//   [0)            QKV bf16 [131072][1536]  (flat; attn overwrites q-cols)
//   [402653184)    XB  bf16 [131072][512]
//   [536870912)    CMB f32 [16w][16h][64][64]
//   [541065216)    SIG f32 [225][16] (pad 16K)
//   [541081600)    WQB bf16 [1536][512]
//   [542654464)    WPB bf16 [512][512]

typedef __attribute__((ext_vector_type(8))) short bf16x8;
typedef __attribute__((ext_vector_type(4))) float f32x4;
typedef __attribute__((ext_vector_type(4))) unsigned short us4;
typedef __attribute__((ext_vector_type(8))) unsigned short us8;
typedef unsigned short u16;
typedef unsigned int u32;

#define FENCE() asm volatile("" ::: "memory")
#define WAITV4() asm volatile("s_waitcnt vmcnt(4)" ::: "memory")
#define WAITV3() asm volatile("s_waitcnt vmcnt(3)" ::: "memory")
#define WAITV0() asm volatile("s_waitcnt vmcnt(0)" ::: "memory")
#define WAITL0() asm volatile("s_waitcnt lgkmcnt(0)" ::: "memory")

__device__ __forceinline__ u16 f2bf(float f) {
  union { __bf16 b; u16 u; } cv;
  cv.b = (__bf16)f;            // hardware RNE convert on gfx950
  return cv.u;
}
__device__ __forceinline__ float bf2f(u16 s) {
  return __uint_as_float(((u32)s) << 16);
}
__device__ __forceinline__ void gl_lds16(const void* g, void* l) {
  __builtin_amdgcn_global_load_lds(
      (const __attribute__((address_space(1))) u32*)g,
      (__attribute__((address_space(3))) u32*)l, 16, 0, 0);
}
__device__ __forceinline__ f32x4 mfma16(bf16x8 a, bf16x8 b, f32x4 c) {
  return __builtin_amdgcn_mfma_f32_16x16x32_bf16(a, b, c, 0, 0, 0);
}
__device__ __forceinline__ bf16x8 ldswz(const u16* p, int ks) {
  return *(const bf16x8*)((const u16*)((uintptr_t)p ^ (uintptr_t)(ks << 6)));
}

// ---------------- K1: merged prep (xconv | conv_w | sig16) ----------------

__global__ void prep_kernel(const float* __restrict__ X, u16* __restrict__ XB,
                            const float* __restrict__ QW, const float* __restrict__ PW,
                            u16* __restrict__ WQB, u16* __restrict__ WPB,
                            const float* __restrict__ CT, const float* __restrict__ W1,
                            const float* __restrict__ B1, const float* __restrict__ W2,
                            float* __restrict__ SIG) {
  const int b = blockIdx.x, tid = threadIdx.x;
  if (b < 32768) {                               // --- xconv ---
    size_t idx = (size_t)b * 256 + tid;          // 8,388,608 threads, 8 f32 each
    float4 a = ((const float4*)X)[idx * 2];
    float4 c = ((const float4*)X)[idx * 2 + 1];
    us8 o;
    o[0] = f2bf(a.x); o[1] = f2bf(a.y); o[2] = f2bf(a.z); o[3] = f2bf(a.w);
    o[4] = f2bf(c.x); o[5] = f2bf(c.y); o[6] = f2bf(c.z); o[7] = f2bf(c.w);
    *(us8*)&XB[idx * 8] = o;
  } else if (b < 33792) {                        // --- conv_w ---
    int idx = (b - 32768) * 256 + tid;           // 262144 float4 chunks
    const int NQ = 1536 * 512 / 4;               // 196608
    float4 v; u16* dst;
    if (idx < NQ) { v = ((const float4*)QW)[idx]; dst = WQB + (size_t)idx * 4; }
    else { int k = idx - NQ; v = ((const float4*)PW)[k]; dst = WPB + (size_t)k * 4; }
    us4 u; u.x = f2bf(v.x); u.y = f2bf(v.y); u.z = f2bf(v.z); u.w = f2bf(v.w);
    *(us4*)dst = u;
  } else {                                       // --- sig16 ---
    int i = b - 33792;                           // 0..224
    float c0 = CT[i * 2 + 0], c1 = CT[i * 2 + 1];
    float a[16];
    #pragma unroll
    for (int hh = 0; hh < 16; ++hh) a[hh] = 0.f;
    #pragma unroll
    for (int jj = 0; jj < 2; ++jj) {
      int j = tid + jj * 256;
      float h = fmaxf(c0 * W1[j * 2 + 0] + c1 * W1[j * 2 + 1] + B1[j], 0.f);
      #pragma unroll
      for (int hh = 0; hh < 16; ++hh) a[hh] += h * W2[hh * 512 + j];
    }
    __shared__ float red[4][16];
    #pragma unroll
    for (int hh = 0; hh < 16; ++hh) {
      float v = a[hh];
      for (int m = 1; m < 64; m <<= 1) v += __shfl_xor(v, m);
      if ((tid & 63) == 0) red[tid >> 6][hh] = v;
    }
    __syncthreads();
    if (tid < 16) {
      float v = red[0][tid] + red[1][tid] + red[2][tid] + red[3][tid];
      SIG[i * 16 + tid] = 16.f / (1.f + __expf(-v));
    }
  }
}

// ---------------- K2: qkv GEMM (double-buffer 48KB, 3 blocks/CU) + cmb tail ----------------
// 128x256, BK=32, 8 waves, 2 bufs x (A 4096 + B 8192) u16 = 49152 B.
// P0(t): read A+B01 frags of buf[t&1]; stage(t+1) into buf[(t+1)&1]
// (WAR-safe: last reads sealed at P1(t-1)'s trailing barrier); bar; lgkm0; 8 MFMA; bar.
// P1(t): read B23; vmcnt(0); bar; lgkm0; 8 MFMA; bar.
// launch_bounds(512,4): natural ~60 VGPR, no spill; occupancy LDS-bound at 3 blocks/CU.

__global__ __launch_bounds__(512, 4) void qkv_g32(
    const u16* __restrict__ XB, const u16* __restrict__ WB,
    const float* __restrict__ QB, const float* __restrict__ VB,
    u16* __restrict__ QKV,
    const float* __restrict__ SIG, const float* __restrict__ MASK,
    const int* __restrict__ RPI, float* __restrict__ CMB) {
  __shared__ u16 S[24576];  // 49152 B
  const int tid = threadIdx.x, lane = tid & 63, w = tid >> 6;
  int bid = blockIdx.x;
  if (bid >= 6144) {                             // --- cmb tail (256 blocks) ---
    int b2 = bid - 6144;
    int mw = b2 >> 4, h = b2 & 15;
    const float* mrow = &MASK[(size_t)mw * 4096];
    float* crow = &CMB[(size_t)b2 * 4096];
    #pragma unroll
    for (int it = 0; it < 8; ++it) {
      int nm = it * 512 + tid;
      crow[nm] = SIG[RPI[nm] * 16 + h] + mrow[nm];
    }
    return;
  }
  int swz = (bid & 7) * 768 + (bid >> 3);         // bijective XCD swizzle
  const int mt = swz / 6, nt = swz - mt * 6;
  const long m0 = (long)mt * 128, n0 = (long)nt * 256;
  const int wm = w >> 2, wn = w & 3;              // 2M x 4N waves; wave tile 64x64
  const int fr = lane & 15, lg = lane >> 4;
  const int fsw = (lg ^ ((fr >> 1) & 3)) << 3;    // swizzled chunk (u16 units)
  const f32x4 zf = {0.f, 0.f, 0.f, 0.f};

  f32x4 acc[4][4];
  #pragma unroll
  for (int mi = 0; mi < 4; ++mi)
    #pragma unroll
    for (int ni = 0; ni < 4; ++ni) acc[mi][ni] = zf;

  const int arow = tid >> 2;
  const int asc = (tid & 3) ^ ((arow >> 1) & 3);
  const u16* aSrc = &XB[(size_t)(m0 + arow) * 512 + asc * 8];
  const u16* bSrc0 = &WB[(size_t)(n0 + arow) * 512 + asc * 8];          // rows 0-127
  const u16* bSrc1 = &WB[(size_t)(n0 + 128 + arow) * 512 + asc * 8];    // rows 128-255

  auto stageT = [&](int kt) {                     // A + both B halves (3 loads)
    int dst = (kt & 1) * 12288;
    gl_lds16(aSrc + kt * 32, &S[dst + w * 512]);
    gl_lds16(bSrc0 + kt * 32, &S[dst + 4096 + w * 512]);
    gl_lds16(bSrc1 + kt * 32, &S[dst + 8192 + w * 512]);
  };

  bf16x8 af[4], bf[2];

  stageT(0);
  WAITV0();
  FENCE(); __builtin_amdgcn_s_barrier(); FENCE();

  #pragma unroll
  for (int t = 0; t < 16; ++t) {
    const int Sb = (t & 1) * 12288;
    // ---- P0 ----
    #pragma unroll
    for (int m = 0; m < 4; ++m)
      af[m] = *(const bf16x8*)&S[Sb + (wm * 64 + m * 16 + fr) * 32 + fsw];
    #pragma unroll
    for (int n = 0; n < 2; ++n)
      bf[n] = *(const bf16x8*)&S[Sb + 4096 + (wn * 64 + n * 16 + fr) * 32 + fsw];
    if (t + 1 <= 15) stageT(t + 1);
    FENCE(); __builtin_amdgcn_s_barrier(); FENCE();
    WAITL0(); __builtin_amdgcn_sched_barrier(0);
    __builtin_amdgcn_s_setprio(1);
    #pragma unroll
    for (int m = 0; m < 4; ++m)
      #pragma unroll
      for (int n = 0; n < 2; ++n)
        acc[m][n] = mfma16(af[m], bf[n], acc[m][n]);
    __builtin_amdgcn_s_setprio(0);
    FENCE(); __builtin_amdgcn_s_barrier(); FENCE();
    // ---- P1 ----
    #pragma unroll
    for (int n = 0; n < 2; ++n)
      bf[n] = *(const bf16x8*)&S[Sb + 4096 + (wn * 64 + (n + 2) * 16 + fr) * 32 + fsw];
    if (t + 1 <= 15) { WAITV0(); }
    FENCE(); __builtin_amdgcn_s_barrier(); FENCE();
    WAITL0(); __builtin_amdgcn_sched_barrier(0);
    __builtin_amdgcn_s_setprio(1);
    #pragma unroll
    for (int m = 0; m < 4; ++m)
      #pragma unroll
      for (int n = 0; n < 2; ++n)
        acc[m][n + 2] = mfma16(af[m], bf[n], acc[m][n + 2]);
    __builtin_amdgcn_s_setprio(0);
    FENCE(); __builtin_amdgcn_s_barrier(); FENCE();
  }

  // Epilogue in two 32-row half-passes (per-wave [32][72] = 4608B, 8 waves = 36864B).
  u16* eb = &S[w * 2304];
  #pragma unroll
  for (int half = 0; half < 2; ++half) {
    #pragma unroll
    for (int ni = 0; ni < 4; ++ni) {
      const long c = n0 + wn * 64 + ni * 16 + fr;
      float bias = (c < 512) ? QB[c] : (c < 1024 ? 0.f : VB[c - 1024]);
      #pragma unroll
      for (int mm = 0; mm < 2; ++mm) {
        const int mi = half * 2 + mm;
        #pragma unroll
        for (int r = 0; r < 4; ++r)
          eb[(mm * 16 + lg * 4 + r) * 72 + ni * 16 + fr] = f2bf(acc[mi][ni][r] + bias);
      }
    }
    WAITL0(); __builtin_amdgcn_sched_barrier(0);
    #pragma unroll
    for (int j = 0; j < 4; ++j) {
      int unit = j * 64 + lane;
      int row32 = unit >> 3, c16 = unit & 7;
      us8 v = *(const us8*)&eb[row32 * 72 + c16 * 8];
      *(us8*)&QKV[(size_t)(m0 + wm * 64 + half * 32 + row32) * 1536 +
                  n0 + wn * 64 + c16 * 8] = v;
    }
    WAITL0(); __builtin_amdgcn_sched_barrier(0);   // reads done before next half's writes
  }
}

// ============ r9 triple-buffer pipeline (for proj) ============

#define GEMM32_KLOOP()                                                     \
  _Pragma("unroll")                                                        \
  for (int t = 0; t < 16; ++t) {                                           \
    const int Sb = (t % 3) * 12288;                                        \
    _Pragma("unroll")                                                      \
    for (int m = 0; m < 4; ++m)                                            \
      af[m] = *(const bf16x8*)&S[Sb + (wm * 64 + m * 16 + fr) * 32 + fsw]; \
    _Pragma("unroll")                                                      \
    for (int n = 0; n < 2; ++n)                                            \
      bf[n] = *(const bf16x8*)&S[Sb + 4096 + (wn * 64 + n * 16 + fr) * 32 + fsw]; \
    if (t + 2 <= 15) stageB(t + 2);                                        \
    FENCE(); __builtin_amdgcn_s_barrier(); FENCE();                        \
    WAITL0(); __builtin_amdgcn_sched_barrier(0);                           \
    __builtin_amdgcn_s_setprio(1);                                         \
    _Pragma("unroll")                                                      \
    for (int m = 0; m < 4; ++m)                                            \
      _Pragma("unroll")                                                    \
      for (int n = 0; n < 2; ++n)                                          \
        acc[m][n] = mfma16(af[m], bf[n], acc[m][n]);                       \
    __builtin_amdgcn_s_setprio(0);                                         \
    FENCE(); __builtin_amdgcn_s_barrier(); FENCE();                        \
    _Pragma("unroll")                                                      \
    for (int n = 0; n < 2; ++n)                                            \
      bf[n] = *(const bf16x8*)&S[Sb + 4096 + (wn * 64 + (n + 2) * 16 + fr) * 32 + fsw]; \
    if (t + 3 <= 15) stageA(t + 3);                                        \
    if (t <= 12) { WAITV4(); }                                             \
    else if (t == 13) { WAITV3(); }                                        \
    else if (t == 14) { WAITV0(); }                                        \
    FENCE(); __builtin_amdgcn_s_barrier(); FENCE();                        \
    WAITL0(); __builtin_amdgcn_sched_barrier(0);                           \
    __builtin_amdgcn_s_setprio(1);                                         \
    _Pragma("unroll")                                                      \
    for (int m = 0; m < 4; ++m)                                            \
      _Pragma("unroll")                                                    \
      for (int n = 0; n < 2; ++n)                                          \
        acc[m][n + 2] = mfma16(af[m], bf[n], acc[m][n + 2]);               \
    __builtin_amdgcn_s_setprio(0);                                         \
    FENCE(); __builtin_amdgcn_s_barrier(); FENCE();                        \
  }

// ---------------- K4: proj GEMM (r9) ----------------

__global__ __launch_bounds__(512, 4) void proj_g32(
    const u16* __restrict__ A, const u16* __restrict__ WB,
    const float* __restrict__ PB, float* __restrict__ OUT) {
  __shared__ u16 S[36864];
  const int tid = threadIdx.x, lane = tid & 63, w = tid >> 6;
  int bid = blockIdx.x;                           // 2048 = 1024m x 2n
  int swz = (bid & 7) * 256 + (bid >> 3);
  const int mt = swz >> 1, nt = swz & 1;
  const long m0 = (long)mt * 128, n0 = (long)nt * 256;
  const int wm = w >> 2, wn = w & 3;
  const int fr = lane & 15, lg = lane >> 4;
  const int fsw = (lg ^ ((fr >> 1) & 3)) << 3;
  const f32x4 zf = {0.f, 0.f, 0.f, 0.f};

  f32x4 acc[4][4];
  #pragma unroll
  for (int mi = 0; mi < 4; ++mi)
    #pragma unroll
    for (int ni = 0; ni < 4; ++ni) acc[mi][ni] = zf;

  const int arow = tid >> 2;
  const int asc = (tid & 3) ^ ((arow >> 1) & 3);
  const u16* aSrc = &A[(size_t)(m0 + arow) * 1536 + asc * 8];           // lda 1536
  const u16* bSrc0 = &WB[(size_t)(n0 + arow) * 512 + asc * 8];
  const u16* bSrc1 = &WB[(size_t)(n0 + 128 + arow) * 512 + asc * 8];

  auto stageA = [&](int kt) {
    gl_lds16(aSrc + kt * 32, &S[(kt % 3) * 12288 + w * 512]);
  };
  auto stageB = [&](int kt) {
    gl_lds16(bSrc0 + kt * 32, &S[(kt % 3) * 12288 + 4096 + w * 512]);
    gl_lds16(bSrc1 + kt * 32, &S[(kt % 3) * 12288 + 8192 + w * 512]);
  };

  bf16x8 af[4], bf[2];

  stageA(0); stageB(0); stageA(1); stageB(1); stageA(2);
  WAITV4();
  FENCE(); __builtin_amdgcn_s_barrier(); FENCE();

  GEMM32_KLOOP()

  #pragma unroll
  for (int ni = 0; ni < 4; ++ni) {
    const long c = n0 + wn * 64 + ni * 16 + fr;
    float bias = PB[c];
    #pragma unroll
    for (int mi = 0; mi < 4; ++mi)
      #pragma unroll
      for (int r = 0; r < 4; ++r) {
        long row = m0 + wm * 64 + mi * 16 + lg * 4 + r;
        OUT[row * 512 + c] = acc[mi][ni][r] + bias;
      }
  }
}

// ---------------- qkv fallback (small ws): reg-staged A, 128x128 ----------------

__global__ __launch_bounds__(256, 2) void qkv_gemm_rs(
    const float* __restrict__ X, const u16* __restrict__ WB,
    const float* __restrict__ QB, const float* __restrict__ VB,
    u16* __restrict__ QKV) {
  __shared__ u16 As[128 * 64];
  __shared__ u16 Bs[128 * 64];
  const int tid = threadIdx.x, lane = tid & 63, w = tid >> 6;
  int bid = blockIdx.x;
  int swz = (bid & 7) * 1536 + (bid >> 3);
  const int mt = swz / 12, nt = swz - mt * 12;
  const long m0 = (long)mt * 128, n0 = (long)nt * 128;
  const int wm = w >> 1, wn = w & 1;
  const f32x4 zf = {0.f, 0.f, 0.f, 0.f};

  f32x4 acc[4][4];
  #pragma unroll
  for (int mi = 0; mi < 4; ++mi)
    #pragma unroll
    for (int ni = 0; ni < 4; ++ni) acc[mi][ni] = zf;

  const int fr = lane & 15;
  const int fsw = ((lane >> 4) ^ (lane & 7)) * 8;
  const u16* Ap = &As[(wm * 64 + fr) * 64 + fsw];
  const u16* Bp = &Bs[(wn * 64 + fr) * 64 + fsw];

  for (int t = 0; t < 8; ++t) {
    float4 av[8];
    #pragma unroll
    for (int i = 0; i < 8; ++i) {
      int ch = tid + (i << 8);
      int row = ch >> 4, kc = ch & 15;
      av[i] = *(const float4*)&X[(m0 + row) * 512 + t * 64 + kc * 4];
    }
    #pragma unroll
    for (int i = 0; i < 4; ++i) {
      int ch = ((w << 2) + i) * 64 + lane;
      int row = ch >> 3, kc = (ch & 7) ^ (row & 7);
      gl_lds16(&WB[(n0 + row) * 512 + t * 64 + kc * 8], &Bs[((w << 2) + i) * 512]);
    }
    #pragma unroll
    for (int i = 0; i < 8; ++i) {
      int ch = tid + (i << 8);
      int row = ch >> 4, kc = ch & 15;
      int kcs = kc ^ ((row & 7) << 1);
      us4 u; u.x = f2bf(av[i].x); u.y = f2bf(av[i].y); u.z = f2bf(av[i].z); u.w = f2bf(av[i].w);
      *(us4*)&As[row * 64 + kcs * 4] = u;
    }
    __syncthreads();
    #pragma unroll
    for (int ks = 0; ks < 2; ++ks) {
      bf16x8 af[4], bfr[4];
      #pragma unroll
      for (int mi = 0; mi < 4; ++mi) af[mi] = ldswz(Ap + mi * 1024, ks);
      #pragma unroll
      for (int ni = 0; ni < 4; ++ni) bfr[ni] = ldswz(Bp + ni * 1024, ks);
      #pragma unroll
      for (int mi = 0; mi < 4; ++mi)
        #pragma unroll
        for (int ni = 0; ni < 4; ++ni)
          acc[mi][ni] = mfma16(af[mi], bfr[ni], acc[mi][ni]);
    }
    __syncthreads();
  }

  #pragma unroll
  for (int ni = 0; ni < 4; ++ni) {
    const long c = n0 + wn * 64 + ni * 16 + (lane & 15);
    float bias = (c < 512) ? QB[c] : (c < 1024 ? 0.f : VB[c - 1024]);
    #pragma unroll
    for (int mi = 0; mi < 4; ++mi)
      #pragma unroll
      for (int r = 0; r < 4; ++r) {
        long row = m0 + wm * 64 + mi * 16 + (lane >> 4) * 4 + r;
        QKV[row * 1536 + c] = f2bf(acc[mi][ni][r] + bias);
      }
  }
}

__global__ void cmb_kernel(const float* __restrict__ SIG, const float* __restrict__ MASK,
                           const int* __restrict__ RPI, float* __restrict__ CMB) {
  int b = blockIdx.x;
  int w = b >> 4, h = b & 15;
  int tid = threadIdx.x;
  const float* mrow = &MASK[(size_t)w * 4096];
  float* crow = &CMB[(size_t)b * 4096];
  #pragma unroll
  for (int it = 0; it < 16; ++it) {
    int nm = it * 256 + tid;
    crow[nm] = SIG[RPI[nm] * 16 + h] + mrow[nm];
  }
}

// ---------------- K3: attention (r10): one (window, head) per wave ----------------

__global__ __launch_bounds__(256, 3) void attn_wh(
    u16* __restrict__ QKV, const float* __restrict__ CMB, const float* __restrict__ LS) {
  __shared__ u16 smu[26112];     // 4 waves x (4352 + 2176) u16 = 52224 B
  const int tid = threadIdx.x, lane = tid & 63, w = tid >> 6;
  const int b = blockIdx.x;
  const int win = b >> 2;        // 0..2047
  const int h = (b & 3) * 4 + w; // head 0..15
  const int wi = win & 15;
  const size_t base = (size_t)win * 64 * 1536;
  const int fr = lane & 15, lg = lane >> 4;
  u16* ps = &smu[w * 6528];      // [64][68]
  u16* vt = ps + 4352;           // [32][68]  (V^T: [d][key])
  const float scale = __expf(fminf(LS[h], 4.6051702f));
  const float* cp = &CMB[((size_t)(wi * 16 + h)) << 12];
  const f32x4 zf = {0.f, 0.f, 0.f, 0.f};

  us8 vrow[4];
  #pragma unroll
  for (int c = 0; c < 4; ++c)
    vrow[c] = *(const us8*)&QKV[base + (size_t)lane * 1536 + 1024 + h * 32 + c * 8];

  f32x4 acc[4][4];
  #pragma unroll
  for (int m = 0; m < 4; ++m)
    #pragma unroll
    for (int n = 0; n < 4; ++n)
      #pragma unroll
      for (int r = 0; r < 4; ++r)
        acc[m][n][r] = cp[(m * 16 + lg * 4 + r) * 64 + n * 16 + fr];

  bf16x8 af[4], bk[4];
  #pragma unroll
  for (int m = 0; m < 4; ++m) {
    us8 qv = *(const us8*)&QKV[base + (size_t)(m * 16 + fr) * 1536 + h * 32 + lg * 8];
    float qf[8]; float ss = 0.f;
    #pragma unroll
    for (int j = 0; j < 8; ++j) { qf[j] = bf2f(qv[j]); ss += qf[j] * qf[j]; }
    ss += __shfl_xor(ss, 16); ss += __shfl_xor(ss, 32);
    float rn = scale / fmaxf(sqrtf(ss), 1e-12f);
    union { us8 u; bf16x8 b; } cv;
    #pragma unroll
    for (int j = 0; j < 8; ++j) cv.u[j] = f2bf(qf[j] * rn);
    af[m] = cv.b;
  }
  #pragma unroll
  for (int m = 0; m < 4; ++m) {
    us8 kv = *(const us8*)&QKV[base + (size_t)(m * 16 + fr) * 1536 + 512 + h * 32 + lg * 8];
    float kf[8]; float ss = 0.f;
    #pragma unroll
    for (int j = 0; j < 8; ++j) { kf[j] = bf2f(kv[j]); ss += kf[j] * kf[j]; }
    ss += __shfl_xor(ss, 16); ss += __shfl_xor(ss, 32);
    float rn = 1.f / fmaxf(sqrtf(ss), 1e-12f);
    union { us8 u; bf16x8 b; } cv;
    #pragma unroll
    for (int j = 0; j < 8; ++j) cv.u[j] = f2bf(kf[j] * rn);
    bk[m] = cv.b;
  }

  #pragma unroll
  for (int m = 0; m < 4; ++m)
    #pragma unroll
    for (int n = 0; n < 4; ++n)
      acc[m][n] = mfma16(af[m], bk[n], acc[m][n]);

  #pragma unroll
  for (int c = 0; c < 4; ++c)
    #pragma unroll
    for (int j = 0; j < 8; ++j)
      vt[(c * 8 + j) * 68 + lane] = vrow[c][j];

  #pragma unroll
  for (int m = 0; m < 4; ++m)
    #pragma unroll
    for (int r = 0; r < 4; ++r) {
      float pv[4];
      float mx = -3.0e38f;
      #pragma unroll
      for (int n = 0; n < 4; ++n) { pv[n] = acc[m][n][r]; mx = fmaxf(mx, pv[n]); }
      mx = fmaxf(mx, __shfl_xor(mx, 1));
      mx = fmaxf(mx, __shfl_xor(mx, 2));
      mx = fmaxf(mx, __shfl_xor(mx, 4));
      mx = fmaxf(mx, __shfl_xor(mx, 8));
      float sum = 0.f;
      #pragma unroll
      for (int n = 0; n < 4; ++n) { pv[n] = __expf(pv[n] - mx); sum += pv[n]; }
      sum += __shfl_xor(sum, 1); sum += __shfl_xor(sum, 2);
      sum += __shfl_xor(sum, 4); sum += __shfl_xor(sum, 8);
      float inv = 1.f / sum;
      #pragma unroll
      for (int n = 0; n < 4; ++n)
        ps[(m * 16 + lg * 4 + r) * 68 + n * 16 + fr] = f2bf(pv[n] * inv);
    }

  WAITL0(); __builtin_amdgcn_sched_barrier(0);

  f32x4 o[4][2];
  #pragma unroll
  for (int m = 0; m < 4; ++m) { o[m][0] = zf; o[m][1] = zf; }
  #pragma unroll
  for (int m = 0; m < 4; ++m)
    #pragma unroll
    for (int ks = 0; ks < 2; ++ks) {
      bf16x8 ap = *(const bf16x8*)&ps[(m * 16 + fr) * 68 + ks * 32 + lg * 8];
      #pragma unroll
      for (int n2 = 0; n2 < 2; ++n2) {
        bf16x8 bv = *(const bf16x8*)&vt[(n2 * 16 + fr) * 68 + ks * 32 + lg * 8];
        o[m][n2] = mfma16(ap, bv, o[m][n2]);
      }
    }

  #pragma unroll
  for (int m = 0; m < 4; ++m)
    #pragma unroll
    for (int n2 = 0; n2 < 2; ++n2)
      #pragma unroll
      for (int r = 0; r < 4; ++r)
        QKV[base + (size_t)(m * 16 + lg * 4 + r) * 1536 + h * 32 + n2 * 16 + fr] =
            f2bf(o[m][n2][r]);
}

// ---------------- launch ----------------

extern "C" void kernel_launch(void* const* d_in, const int* in_sizes, int n_in,
                              void* d_out, int out_size, void* d_ws, size_t ws_size,
                              hipStream_t stream) {
  const float* X    = (const float*)d_in[0];
  const float* MASK = (const float*)d_in[1];
  const float* QW   = (const float*)d_in[2];
  const float* QB   = (const float*)d_in[3];
  const float* VB   = (const float*)d_in[4];
  const float* LS   = (const float*)d_in[5];
  const float* CW1  = (const float*)d_in[6];
  const float* CB1  = (const float*)d_in[7];
  const float* CW2  = (const float*)d_in[8];
  const float* PW   = (const float*)d_in[9];
  const float* PB   = (const float*)d_in[10];
  const float* CT   = (const float*)d_in[11];
  const int*   RPI  = (const int*)d_in[12];
  float* OUT = (float*)d_out;

  char* ws = (char*)d_ws;
  const bool big = ws_size >= 543178752ull;
  u16* QKV = (u16*)ws;                                    // 402,653,184 B
  u16* XB  = (u16*)(ws + 402653184ull);                   // 134,217,728 B (big only)
  size_t off = big ? 536870912ull : 402653184ull;
  float* CMB = (float*)(ws + off);  off += 4194304ull;    // 4 MB
  float* SIG = (float*)(ws + off);  off += 16384ull;
  u16*   WQB = (u16*)(ws + off);    off += 1572864ull;
  u16*   WPB = (u16*)(ws + off);

  if (big) {
    prep_kernel<<<34017, 256, 0, stream>>>(X, XB, QW, PW, WQB, WPB,
                                           CT, CW1, CB1, CW2, SIG);
    qkv_g32<<<6400, 512, 0, stream>>>(XB, WQB, QB, VB, QKV, SIG, MASK, RPI, CMB);
  } else {
    prep_kernel<<<34017, 256, 0, stream>>>(X, XB, QW, PW, WQB, WPB,
                                           CT, CW1, CB1, CW2, SIG);
    cmb_kernel<<<256, 256, 0, stream>>>(SIG, MASK, RPI, CMB);
    qkv_gemm_rs<<<12288, 256, 0, stream>>>(X, WQB, QB, VB, QKV);
  }
  attn_wh<<<8192, 256, 0, stream>>>(QKV, CMB, LS);
  proj_g32<<<2048, 512, 0, stream>>>(QKV, WPB, PB, OUT);
}

// Round 18
// 632.329 us; speedup vs baseline: 3.3340x; 1.0484x over previous
//
#include <hip/hip_runtime.h>
#include <stdint.h>
#include <stddef.h>

// SwinV2-B stage-3 window attention, MI355X bf16-MFMA pipeline.
// Round 18: revert to round-15 exactly (best measured, 633.8us).
//   K1 prep = xconv|conv_w|sig16; K2 qkv (triple-buffer, counted vmcnt(4),
//   2 blocks/CU) + cmb tail; K3 attn (r10 wave-per-head); K4 proj (r9).
// Big ws layout (ws_size >= 543,178,752 B):
//   [0)            QKV bf16 [131072][1536]  (flat; attn overwrites q-cols)
//   [402653184)    XB  bf16 [131072][512]
//   [536870912)    CMB f32 [16w][16h][64][64]
//   [541065216)    SIG f32 [225][16] (pad 16K)
//   [541081600)    WQB bf16 [1536][512]
//   [542654464)    WPB bf16 [512][512]

typedef __attribute__((ext_vector_type(8))) short bf16x8;
typedef __attribute__((ext_vector_type(4))) float f32x4;
typedef __attribute__((ext_vector_type(4))) unsigned short us4;
typedef __attribute__((ext_vector_type(8))) unsigned short us8;
typedef unsigned short u16;
typedef unsigned int u32;

#define FENCE() asm volatile("" ::: "memory")
#define WAITV4() asm volatile("s_waitcnt vmcnt(4)" ::: "memory")
#define WAITV3() asm volatile("s_waitcnt vmcnt(3)" ::: "memory")
#define WAITV0() asm volatile("s_waitcnt vmcnt(0)" ::: "memory")
#define WAITL0() asm volatile("s_waitcnt lgkmcnt(0)" ::: "memory")

__device__ __forceinline__ u16 f2bf(float f) {
  union { __bf16 b; u16 u; } cv;
  cv.b = (__bf16)f;            // hardware RNE convert on gfx950
  return cv.u;
}
__device__ __forceinline__ float bf2f(u16 s) {
  return __uint_as_float(((u32)s) << 16);
}
__device__ __forceinline__ void gl_lds16(const void* g, void* l) {
  __builtin_amdgcn_global_load_lds(
      (const __attribute__((address_space(1))) u32*)g,
      (__attribute__((address_space(3))) u32*)l, 16, 0, 0);
}
__device__ __forceinline__ f32x4 mfma16(bf16x8 a, bf16x8 b, f32x4 c) {
  return __builtin_amdgcn_mfma_f32_16x16x32_bf16(a, b, c, 0, 0, 0);
}
__device__ __forceinline__ bf16x8 ldswz(const u16* p, int ks) {
  return *(const bf16x8*)((const u16*)((uintptr_t)p ^ (uintptr_t)(ks << 6)));
}

// ---------------- K1: merged prep (xconv | conv_w | sig16) ----------------

__global__ void prep_kernel(const float* __restrict__ X, u16* __restrict__ XB,
                            const float* __restrict__ QW, const float* __restrict__ PW,
                            u16* __restrict__ WQB, u16* __restrict__ WPB,
                            const float* __restrict__ CT, const float* __restrict__ W1,
                            const float* __restrict__ B1, const float* __restrict__ W2,
                            float* __restrict__ SIG) {
  const int b = blockIdx.x, tid = threadIdx.x;
  if (b < 32768) {                               // --- xconv ---
    size_t idx = (size_t)b * 256 + tid;          // 8,388,608 threads, 8 f32 each
    float4 a = ((const float4*)X)[idx * 2];
    float4 c = ((const float4*)X)[idx * 2 + 1];
    us8 o;
    o[0] = f2bf(a.x); o[1] = f2bf(a.y); o[2] = f2bf(a.z); o[3] = f2bf(a.w);
    o[4] = f2bf(c.x); o[5] = f2bf(c.y); o[6] = f2bf(c.z); o[7] = f2bf(c.w);
    *(us8*)&XB[idx * 8] = o;
  } else if (b < 33792) {                        // --- conv_w ---
    int idx = (b - 32768) * 256 + tid;           // 262144 float4 chunks
    const int NQ = 1536 * 512 / 4;               // 196608
    float4 v; u16* dst;
    if (idx < NQ) { v = ((const float4*)QW)[idx]; dst = WQB + (size_t)idx * 4; }
    else { int k = idx - NQ; v = ((const float4*)PW)[k]; dst = WPB + (size_t)k * 4; }
    us4 u; u.x = f2bf(v.x); u.y = f2bf(v.y); u.z = f2bf(v.z); u.w = f2bf(v.w);
    *(us4*)dst = u;
  } else {                                       // --- sig16 ---
    int i = b - 33792;                           // 0..224
    float c0 = CT[i * 2 + 0], c1 = CT[i * 2 + 1];
    float a[16];
    #pragma unroll
    for (int hh = 0; hh < 16; ++hh) a[hh] = 0.f;
    #pragma unroll
    for (int jj = 0; jj < 2; ++jj) {
      int j = tid + jj * 256;
      float h = fmaxf(c0 * W1[j * 2 + 0] + c1 * W1[j * 2 + 1] + B1[j], 0.f);
      #pragma unroll
      for (int hh = 0; hh < 16; ++hh) a[hh] += h * W2[hh * 512 + j];
    }
    __shared__ float red[4][16];
    #pragma unroll
    for (int hh = 0; hh < 16; ++hh) {
      float v = a[hh];
      for (int m = 1; m < 64; m <<= 1) v += __shfl_xor(v, m);
      if ((tid & 63) == 0) red[tid >> 6][hh] = v;
    }
    __syncthreads();
    if (tid < 16) {
      float v = red[0][tid] + red[1][tid] + red[2][tid] + red[3][tid];
      SIG[i * 16 + tid] = 16.f / (1.f + __expf(-v));
    }
  }
}

// ============ 128x256 / BK=32 / 8-wave / triple-buffer pipeline ============

#define GEMM32_KLOOP()                                                     \
  _Pragma("unroll")                                                        \
  for (int t = 0; t < 16; ++t) {                                           \
    const int Sb = (t % 3) * 12288;                                        \
    _Pragma("unroll")                                                      \
    for (int m = 0; m < 4; ++m)                                            \
      af[m] = *(const bf16x8*)&S[Sb + (wm * 64 + m * 16 + fr) * 32 + fsw]; \
    _Pragma("unroll")                                                      \
    for (int n = 0; n < 2; ++n)                                            \
      bf[n] = *(const bf16x8*)&S[Sb + 4096 + (wn * 64 + n * 16 + fr) * 32 + fsw]; \
    if (t + 2 <= 15) stageB(t + 2);                                        \
    FENCE(); __builtin_amdgcn_s_barrier(); FENCE();                        \
    WAITL0(); __builtin_amdgcn_sched_barrier(0);                           \
    __builtin_amdgcn_s_setprio(1);                                         \
    _Pragma("unroll")                                                      \
    for (int m = 0; m < 4; ++m)                                            \
      _Pragma("unroll")                                                    \
      for (int n = 0; n < 2; ++n)                                          \
        acc[m][n] = mfma16(af[m], bf[n], acc[m][n]);                       \
    __builtin_amdgcn_s_setprio(0);                                         \
    FENCE(); __builtin_amdgcn_s_barrier(); FENCE();                        \
    _Pragma("unroll")                                                      \
    for (int n = 0; n < 2; ++n)                                            \
      bf[n] = *(const bf16x8*)&S[Sb + 4096 + (wn * 64 + (n + 2) * 16 + fr) * 32 + fsw]; \
    if (t + 3 <= 15) stageA(t + 3);                                        \
    if (t <= 12) { WAITV4(); }                                             \
    else if (t == 13) { WAITV3(); }                                        \
    else if (t == 14) { WAITV0(); }                                        \
    FENCE(); __builtin_amdgcn_s_barrier(); FENCE();                        \
    WAITL0(); __builtin_amdgcn_sched_barrier(0);                           \
    __builtin_amdgcn_s_setprio(1);                                         \
    _Pragma("unroll")                                                      \
    for (int m = 0; m < 4; ++m)                                            \
      _Pragma("unroll")                                                    \
      for (int n = 0; n < 2; ++n)                                          \
        acc[m][n + 2] = mfma16(af[m], bf[n], acc[m][n + 2]);               \
    __builtin_amdgcn_s_setprio(0);                                         \
    FENCE(); __builtin_amdgcn_s_barrier(); FENCE();                        \
  }

// ---------------- K2: qkv GEMM (r10) + cmb tail blocks ----------------

__global__ __launch_bounds__(512, 4) void qkv_g32(
    const u16* __restrict__ XB, const u16* __restrict__ WB,
    const float* __restrict__ QB, const float* __restrict__ VB,
    u16* __restrict__ QKV,
    const float* __restrict__ SIG, const float* __restrict__ MASK,
    const int* __restrict__ RPI, float* __restrict__ CMB) {
  __shared__ u16 S[36864];  // 3 x (A 4096 + B 8192) u16 = 73728 B
  const int tid = threadIdx.x, lane = tid & 63, w = tid >> 6;
  int bid = blockIdx.x;
  if (bid >= 6144) {                             // --- cmb tail (256 blocks) ---
    int b2 = bid - 6144;
    int mw = b2 >> 4, h = b2 & 15;
    const float* mrow = &MASK[(size_t)mw * 4096];
    float* crow = &CMB[(size_t)b2 * 4096];
    #pragma unroll
    for (int it = 0; it < 8; ++it) {
      int nm = it * 512 + tid;
      crow[nm] = SIG[RPI[nm] * 16 + h] + mrow[nm];
    }
    return;
  }
  int swz = (bid & 7) * 768 + (bid >> 3);         // bijective XCD swizzle
  const int mt = swz / 6, nt = swz - mt * 6;
  const long m0 = (long)mt * 128, n0 = (long)nt * 256;
  const int wm = w >> 2, wn = w & 3;              // 2M x 4N waves; wave tile 64x64
  const int fr = lane & 15, lg = lane >> 4;
  const int fsw = (lg ^ ((fr >> 1) & 3)) << 3;    // swizzled chunk (u16 units)
  const f32x4 zf = {0.f, 0.f, 0.f, 0.f};

  f32x4 acc[4][4];
  #pragma unroll
  for (int mi = 0; mi < 4; ++mi)
    #pragma unroll
    for (int ni = 0; ni < 4; ++ni) acc[mi][ni] = zf;

  const int arow = tid >> 2;
  const int asc = (tid & 3) ^ ((arow >> 1) & 3);
  const u16* aSrc = &XB[(size_t)(m0 + arow) * 512 + asc * 8];
  const u16* bSrc0 = &WB[(size_t)(n0 + arow) * 512 + asc * 8];          // rows 0-127
  const u16* bSrc1 = &WB[(size_t)(n0 + 128 + arow) * 512 + asc * 8];    // rows 128-255

  auto stageA = [&](int kt) {
    gl_lds16(aSrc + kt * 32, &S[(kt % 3) * 12288 + w * 512]);
  };
  auto stageB = [&](int kt) {
    gl_lds16(bSrc0 + kt * 32, &S[(kt % 3) * 12288 + 4096 + w * 512]);
    gl_lds16(bSrc1 + kt * 32, &S[(kt % 3) * 12288 + 8192 + w * 512]);
  };

  bf16x8 af[4], bf[2];

  stageA(0); stageB(0); stageA(1); stageB(1); stageA(2);
  WAITV4();
  FENCE(); __builtin_amdgcn_s_barrier(); FENCE();

  GEMM32_KLOOP()

  // LDS-staged epilogue: per-wave [64][72] bf16 tile, then full-line us8 stores.
  u16* eb = &S[w * 4608];   // 64*72 u16 = 9216 B per wave
  #pragma unroll
  for (int ni = 0; ni < 4; ++ni) {
    const long c = n0 + wn * 64 + ni * 16 + fr;
    float bias = (c < 512) ? QB[c] : (c < 1024 ? 0.f : VB[c - 1024]);
    #pragma unroll
    for (int mi = 0; mi < 4; ++mi)
      #pragma unroll
      for (int r = 0; r < 4; ++r)
        eb[(mi * 16 + lg * 4 + r) * 72 + ni * 16 + fr] = f2bf(acc[mi][ni][r] + bias);
  }
  WAITL0();
  #pragma unroll
  for (int i = 0; i < 8; ++i) {
    int row = i * 8 + (lane >> 3);
    int c16 = lane & 7;
    us8 v = *(const us8*)&eb[row * 72 + c16 * 8];
    *(us8*)&QKV[(size_t)(m0 + wm * 64 + row) * 1536 + n0 + wn * 64 + c16 * 8] = v;
  }
}

// ---------------- K4: proj GEMM (r9) ----------------

__global__ __launch_bounds__(512, 4) void proj_g32(
    const u16* __restrict__ A, const u16* __restrict__ WB,
    const float* __restrict__ PB, float* __restrict__ OUT) {
  __shared__ u16 S[36864];
  const int tid = threadIdx.x, lane = tid & 63, w = tid >> 6;
  int bid = blockIdx.x;                           // 2048 = 1024m x 2n
  int swz = (bid & 7) * 256 + (bid >> 3);
  const int mt = swz >> 1, nt = swz & 1;
  const long m0 = (long)mt * 128, n0 = (long)nt * 256;
  const int wm = w >> 2, wn = w & 3;
  const int fr = lane & 15, lg = lane >> 4;
  const int fsw = (lg ^ ((fr >> 1) & 3)) << 3;
  const f32x4 zf = {0.f, 0.f, 0.f, 0.f};

  f32x4 acc[4][4];
  #pragma unroll
  for (int mi = 0; mi < 4; ++mi)
    #pragma unroll
    for (int ni = 0; ni < 4; ++ni) acc[mi][ni] = zf;

  const int arow = tid >> 2;
  const int asc = (tid & 3) ^ ((arow >> 1) & 3);
  const u16* aSrc = &A[(size_t)(m0 + arow) * 1536 + asc * 8];           // lda 1536
  const u16* bSrc0 = &WB[(size_t)(n0 + arow) * 512 + asc * 8];
  const u16* bSrc1 = &WB[(size_t)(n0 + 128 + arow) * 512 + asc * 8];

  auto stageA = [&](int kt) {
    gl_lds16(aSrc + kt * 32, &S[(kt % 3) * 12288 + w * 512]);
  };
  auto stageB = [&](int kt) {
    gl_lds16(bSrc0 + kt * 32, &S[(kt % 3) * 12288 + 4096 + w * 512]);
    gl_lds16(bSrc1 + kt * 32, &S[(kt % 3) * 12288 + 8192 + w * 512]);
  };

  bf16x8 af[4], bf[2];

  stageA(0); stageB(0); stageA(1); stageB(1); stageA(2);
  WAITV4();
  FENCE(); __builtin_amdgcn_s_barrier(); FENCE();

  GEMM32_KLOOP()

  #pragma unroll
  for (int ni = 0; ni < 4; ++ni) {
    const long c = n0 + wn * 64 + ni * 16 + fr;
    float bias = PB[c];
    #pragma unroll
    for (int mi = 0; mi < 4; ++mi)
      #pragma unroll
      for (int r = 0; r < 4; ++r) {
        long row = m0 + wm * 64 + mi * 16 + lg * 4 + r;
        OUT[row * 512 + c] = acc[mi][ni][r] + bias;
      }
  }
}

// ---------------- qkv fallback (small ws): reg-staged A, 128x128 ----------------

__global__ __launch_bounds__(256, 2) void qkv_gemm_rs(
    const float* __restrict__ X, const u16* __restrict__ WB,
    const float* __restrict__ QB, const float* __restrict__ VB,
    u16* __restrict__ QKV) {
  __shared__ u16 As[128 * 64];
  __shared__ u16 Bs[128 * 64];
  const int tid = threadIdx.x, lane = tid & 63, w = tid >> 6;
  int bid = blockIdx.x;
  int swz = (bid & 7) * 1536 + (bid >> 3);
  const int mt = swz / 12, nt = swz - mt * 12;
  const long m0 = (long)mt * 128, n0 = (long)nt * 128;
  const int wm = w >> 1, wn = w & 1;
  const f32x4 zf = {0.f, 0.f, 0.f, 0.f};

  f32x4 acc[4][4];
  #pragma unroll
  for (int mi = 0; mi < 4; ++mi)
    #pragma unroll
    for (int ni = 0; ni < 4; ++ni) acc[mi][ni] = zf;

  const int fr = lane & 15;
  const int fsw = ((lane >> 4) ^ (lane & 7)) * 8;
  const u16* Ap = &As[(wm * 64 + fr) * 64 + fsw];
  const u16* Bp = &Bs[(wn * 64 + fr) * 64 + fsw];

  for (int t = 0; t < 8; ++t) {
    float4 av[8];
    #pragma unroll
    for (int i = 0; i < 8; ++i) {
      int ch = tid + (i << 8);
      int row = ch >> 4, kc = ch & 15;
      av[i] = *(const float4*)&X[(m0 + row) * 512 + t * 64 + kc * 4];
    }
    #pragma unroll
    for (int i = 0; i < 4; ++i) {
      int ch = ((w << 2) + i) * 64 + lane;
      int row = ch >> 3, kc = (ch & 7) ^ (row & 7);
      gl_lds16(&WB[(n0 + row) * 512 + t * 64 + kc * 8], &Bs[((w << 2) + i) * 512]);
    }
    #pragma unroll
    for (int i = 0; i < 8; ++i) {
      int ch = tid + (i << 8);
      int row = ch >> 4, kc = ch & 15;
      int kcs = kc ^ ((row & 7) << 1);
      us4 u; u.x = f2bf(av[i].x); u.y = f2bf(av[i].y); u.z = f2bf(av[i].z); u.w = f2bf(av[i].w);
      *(us4*)&As[row * 64 + kcs * 4] = u;
    }
    __syncthreads();
    #pragma unroll
    for (int ks = 0; ks < 2; ++ks) {
      bf16x8 af[4], bfr[4];
      #pragma unroll
      for (int mi = 0; mi < 4; ++mi) af[mi] = ldswz(Ap + mi * 1024, ks);
      #pragma unroll
      for (int ni = 0; ni < 4; ++ni) bfr[ni] = ldswz(Bp + ni * 1024, ks);
      #pragma unroll
      for (int mi = 0; mi < 4; ++mi)
        #pragma unroll
        for (int ni = 0; ni < 4; ++ni)
          acc[mi][ni] = mfma16(af[mi], bfr[ni], acc[mi][ni]);
    }
    __syncthreads();
  }

  #pragma unroll
  for (int ni = 0; ni < 4; ++ni) {
    const long c = n0 + wn * 64 + ni * 16 + (lane & 15);
    float bias = (c < 512) ? QB[c] : (c < 1024 ? 0.f : VB[c - 1024]);
    #pragma unroll
    for (int mi = 0; mi < 4; ++mi)
      #pragma unroll
      for (int r = 0; r < 4; ++r) {
        long row = m0 + wm * 64 + mi * 16 + (lane >> 4) * 4 + r;
        QKV[row * 1536 + c] = f2bf(acc[mi][ni][r] + bias);
      }
  }
}

__global__ void cmb_kernel(const float* __restrict__ SIG, const float* __restrict__ MASK,
                           const int* __restrict__ RPI, float* __restrict__ CMB) {
  int b = blockIdx.x;
  int w = b >> 4, h = b & 15;
  int tid = threadIdx.x;
  const float* mrow = &MASK[(size_t)w * 4096];
  float* crow = &CMB[(size_t)b * 4096];
  #pragma unroll
  for (int it = 0; it < 16; ++it) {
    int nm = it * 256 + tid;
    crow[nm] = SIG[RPI[nm] * 16 + h] + mrow[nm];
  }
}

// ---------------- K3: attention (r10): one (window, head) per wave ----------------

__global__ __launch_bounds__(256, 3) void attn_wh(
    u16* __restrict__ QKV, const float* __restrict__ CMB, const float* __restrict__ LS) {
  __shared__ u16 smu[26112];     // 4 waves x (4352 + 2176) u16 = 52224 B
  const int tid = threadIdx.x, lane = tid & 63, w = tid >> 6;
  const int b = blockIdx.x;
  const int win = b >> 2;        // 0..2047
  const int h = (b & 3) * 4 + w; // head 0..15
  const int wi = win & 15;
  const size_t base = (size_t)win * 64 * 1536;
  const int fr = lane & 15, lg = lane >> 4;
  u16* ps = &smu[w * 6528];      // [64][68]
  u16* vt = ps + 4352;           // [32][68]  (V^T: [d][key])
  const float scale = __expf(fminf(LS[h], 4.6051702f));
  const float* cp = &CMB[((size_t)(wi * 16 + h)) << 12];
  const f32x4 zf = {0.f, 0.f, 0.f, 0.f};

  us8 vrow[4];
  #pragma unroll
  for (int c = 0; c < 4; ++c)
    vrow[c] = *(const us8*)&QKV[base + (size_t)lane * 1536 + 1024 + h * 32 + c * 8];

  f32x4 acc[4][4];
  #pragma unroll
  for (int m = 0; m < 4; ++m)
    #pragma unroll
    for (int n = 0; n < 4; ++n)
      #pragma unroll
      for (int r = 0; r < 4; ++r)
        acc[m][n][r] = cp[(m * 16 + lg * 4 + r) * 64 + n * 16 + fr];

  bf16x8 af[4], bk[4];
  #pragma unroll
  for (int m = 0; m < 4; ++m) {
    us8 qv = *(const us8*)&QKV[base + (size_t)(m * 16 + fr) * 1536 + h * 32 + lg * 8];
    float qf[8]; float ss = 0.f;
    #pragma unroll
    for (int j = 0; j < 8; ++j) { qf[j] = bf2f(qv[j]); ss += qf[j] * qf[j]; }
    ss += __shfl_xor(ss, 16); ss += __shfl_xor(ss, 32);
    float rn = scale / fmaxf(sqrtf(ss), 1e-12f);
    union { us8 u; bf16x8 b; } cv;
    #pragma unroll
    for (int j = 0; j < 8; ++j) cv.u[j] = f2bf(qf[j] * rn);
    af[m] = cv.b;
  }
  #pragma unroll
  for (int m = 0; m < 4; ++m) {
    us8 kv = *(const us8*)&QKV[base + (size_t)(m * 16 + fr) * 1536 + 512 + h * 32 + lg * 8];
    float kf[8]; float ss = 0.f;
    #pragma unroll
    for (int j = 0; j < 8; ++j) { kf[j] = bf2f(kv[j]); ss += kf[j] * kf[j]; }
    ss += __shfl_xor(ss, 16); ss += __shfl_xor(ss, 32);
    float rn = 1.f / fmaxf(sqrtf(ss), 1e-12f);
    union { us8 u; bf16x8 b; } cv;
    #pragma unroll
    for (int j = 0; j < 8; ++j) cv.u[j] = f2bf(kf[j] * rn);
    bk[m] = cv.b;
  }

  #pragma unroll
  for (int m = 0; m < 4; ++m)
    #pragma unroll
    for (int n = 0; n < 4; ++n)
      acc[m][n] = mfma16(af[m], bk[n], acc[m][n]);

  #pragma unroll
  for (int c = 0; c < 4; ++c)
    #pragma unroll
    for (int j = 0; j < 8; ++j)
      vt[(c * 8 + j) * 68 + lane] = vrow[c][j];

  #pragma unroll
  for (int m = 0; m < 4; ++m)
    #pragma unroll
    for (int r = 0; r < 4; ++r) {
      float pv[4];
      float mx = -3.0e38f;
      #pragma unroll
      for (int n = 0; n < 4; ++n) { pv[n] = acc[m][n][r]; mx = fmaxf(mx, pv[n]); }
      mx = fmaxf(mx, __shfl_xor(mx, 1));
      mx = fmaxf(mx, __shfl_xor(mx, 2));
      mx = fmaxf(mx, __shfl_xor(mx, 4));
      mx = fmaxf(mx, __shfl_xor(mx, 8));
      float sum = 0.f;
      #pragma unroll
      for (int n = 0; n < 4; ++n) { pv[n] = __expf(pv[n] - mx); sum += pv[n]; }
      sum += __shfl_xor(sum, 1); sum += __shfl_xor(sum, 2);
      sum += __shfl_xor(sum, 4); sum += __shfl_xor(sum, 8);
      float inv = 1.f / sum;
      #pragma unroll
      for (int n = 0; n < 4; ++n)
        ps[(m * 16 + lg * 4 + r) * 68 + n * 16 + fr] = f2bf(pv[n] * inv);
    }

  WAITL0(); __builtin_amdgcn_sched_barrier(0);

  f32x4 o[4][2];
  #pragma unroll
  for (int m = 0; m < 4; ++m) { o[m][0] = zf; o[m][1] = zf; }
  #pragma unroll
  for (int m = 0; m < 4; ++m)
    #pragma unroll
    for (int ks = 0; ks < 2; ++ks) {
      bf16x8 ap = *(const bf16x8*)&ps[(m * 16 + fr) * 68 + ks * 32 + lg * 8];
      #pragma unroll
      for (int n2 = 0; n2 < 2; ++n2) {
        bf16x8 bv = *(const bf16x8*)&vt[(n2 * 16 + fr) * 68 + ks * 32 + lg * 8];
        o[m][n2] = mfma16(ap, bv, o[m][n2]);
      }
    }

  #pragma unroll
  for (int m = 0; m < 4; ++m)
    #pragma unroll
    for (int n2 = 0; n2 < 2; ++n2)
      #pragma unroll
      for (int r = 0; r < 4; ++r)
        QKV[base + (size_t)(m * 16 + lg * 4 + r) * 1536 + h * 32 + n2 * 16 + fr] =
            f2bf(o[m][n2][r]);
}

// ---------------- launch ----------------

extern "C" void kernel_launch(void* const* d_in, const int* in_sizes, int n_in,
                              void* d_out, int out_size, void* d_ws, size_t ws_size,
                              hipStream_t stream) {
  const float* X    = (const float*)d_in[0];
  const float* MASK = (const float*)d_in[1];
  const float* QW   = (const float*)d_in[2];
  const float* QB   = (const float*)d_in[3];
  const float* VB   = (const float*)d_in[4];
  const float* LS   = (const float*)d_in[5];
  const float* CW1  = (const float*)d_in[6];
  const float* CB1  = (const float*)d_in[7];
  const float* CW2  = (const float*)d_in[8];
  const float* PW   = (const float*)d_in[9];
  const float* PB   = (const float*)d_in[10];
  const float* CT   = (const float*)d_in[11];
  const int*   RPI  = (const int*)d_in[12];
  float* OUT = (float*)d_out;

  char* ws = (char*)d_ws;
  const bool big = ws_size >= 543178752ull;
  u16* QKV = (u16*)ws;                                    // 402,653,184 B
  u16* XB  = (u16*)(ws + 402653184ull);                   // 134,217,728 B (big only)
  size_t off = big ? 536870912ull : 402653184ull;
  float* CMB = (float*)(ws + off);  off += 4194304ull;    // 4 MB
  float* SIG = (float*)(ws + off);  off += 16384ull;
  u16*   WQB = (u16*)(ws + off);    off += 1572864ull;
  u16*   WPB = (u16*)(ws + off);

  if (big) {
    prep_kernel<<<34017, 256, 0, stream>>>(X, XB, QW, PW, WQB, WPB,
                                           CT, CW1, CB1, CW2, SIG);
    qkv_g32<<<6400, 512, 0, stream>>>(XB, WQB, QB, VB, QKV, SIG, MASK, RPI, CMB);
  } else {
    prep_kernel<<<34017, 256, 0, stream>>>(X, XB, QW, PW, WQB, WPB,
                                           CT, CW1, CB1, CW2, SIG);
    cmb_kernel<<<256, 256, 0, stream>>>(SIG, MASK, RPI, CMB);
    qkv_gemm_rs<<<12288, 256, 0, stream>>>(X, WQB, QB, VB, QKV);
  }
  attn_wh<<<8192, 256, 0, stream>>>(QKV, CMB, LS);
  proj_g32<<<2048, 512, 0, stream>>>(QKV, WPB, PB, OUT);
}